// Round 3
// baseline (2907.759 us; speedup 1.0000x reference)
//
#include <hip/hip_runtime.h>
#include <hip/hip_bf16.h>

#define K_ITERS 20
#define F_IN 512
#define F_HID 128
#define F_OUT 40
#define SCAN_CHUNK 512

// Dataset is FP32 end-to-end (established round 3/6). Output buffer fp32 (16 MB).
// R9 changes:
//  - CSR rows padded to multiple of 8 (dummy edges norm=0,src=0 via memset) ->
//    k_prop has NO scalar tail (the avg ~3.5 serial full-latency edges/node
//    were the dominant cost). Scans sum padded counts; row_ptr[N]=E_pad.
//  - k_prop: 2-deep named-buffer pipeline (16 gathers in flight, counted
//    vmcnt); self/h0 loads hoisted above loop.
//  - k_mlp: W1 LDS staging dropped (direct L1/L2 vector loads; no per-kt
//    barriers -> waves desync and self-hide latency). x register-prefetched
//    2 chunks deep. Tile = 4 nodes x 8 hids per thread.

// ---------- in-degree histogram over col (targets) ----------
__global__ void k_hist(const int* __restrict__ col, int E, int* __restrict__ cnt){
  int e = blockIdx.x*blockDim.x + threadIdx.x;
  if (e < E) atomicAdd(&cnt[col[e]], 1);
}

// ---------- dinv = rsqrt(in_deg + 1) ----------
__global__ void k_dinv(const int* __restrict__ cnt, int N, float* __restrict__ dinv){
  int i = blockIdx.x*blockDim.x + threadIdx.x;
  if (i < N) dinv[i] = rsqrtf((float)(cnt[i] + 1));
}

// ---------- scan phase 1 (padded counts) ----------
__global__ void k_scan1(const int* __restrict__ cnt, int N, int* __restrict__ bsum){
  __shared__ int sd[256];
  int base = blockIdx.x * SCAN_CHUNK;
  int t = threadIdx.x;
  int i0 = base + 2*t, i1 = i0+1;
  int c0 = (i0<N)? ((cnt[i0]+7)&~7) : 0;
  int c1 = (i1<N)? ((cnt[i1]+7)&~7) : 0;
  int s = c0 + c1;
  sd[t] = s; __syncthreads();
  for (int off=1; off<256; off<<=1){
    int v = (t>=off)? sd[t-off] : 0;
    __syncthreads();
    sd[t] += v;
    __syncthreads();
  }
  if (t==255) bsum[blockIdx.x] = sd[255];
}
// ---------- scan phase 2 ----------
__global__ void k_scan2(const int* __restrict__ bsum, int NB, int* __restrict__ boff,
                        int* __restrict__ row_ptr, int N, int E){
  __shared__ int sd[256];
  int t = threadIdx.x;
  int v = (t < NB) ? bsum[t] : 0;
  sd[t] = v; __syncthreads();
  for (int off=1; off<256; off<<=1){
    int u = (t>=off)? sd[t-off] : 0;
    __syncthreads();
    sd[t] += u;
    __syncthreads();
  }
  if (t < NB) boff[t] = sd[t] - v;
  if (t == NB-1) row_ptr[N] = sd[t];   // E_pad total
}
// ---------- scan phase 3 (padded counts) ----------
__global__ void k_scan3(const int* __restrict__ cnt, int N, const int* __restrict__ boff,
                        int* __restrict__ row_ptr){
  __shared__ int sd[256];
  int base = blockIdx.x * SCAN_CHUNK;
  int t = threadIdx.x;
  int i0 = base + 2*t, i1 = i0+1;
  int c0 = (i0<N)? ((cnt[i0]+7)&~7) : 0;
  int c1 = (i1<N)? ((cnt[i1]+7)&~7) : 0;
  int s = c0+c1;
  sd[t] = s; __syncthreads();
  for (int off=1; off<256; off<<=1){
    int v = (t>=off)? sd[t-off] : 0;
    __syncthreads();
    sd[t] += v;
    __syncthreads();
  }
  int excl = sd[t] - s + boff[blockIdx.x];
  if (i0<N) row_ptr[i0] = excl;
  if (i1<N) row_ptr[i1] = excl + c0;
}

// ---------- CSR scatter by target ----------
__global__ void k_scatter(const int* __restrict__ row, const int* __restrict__ col, int E,
                          const int* __restrict__ row_ptr, int* __restrict__ cur,
                          const float* __restrict__ dinv,
                          int* __restrict__ csr_src, float* __restrict__ csr_norm){
  int e = blockIdx.x*blockDim.x + threadIdx.x;
  if (e >= E) return;
  int r = row[e], c = col[e];
  int p = row_ptr[c] + atomicAdd(&cur[c], 1);
  csr_src[p] = r;
  csr_norm[p] = dinv[r]*dinv[c];
}

// ---------- fused MLP ----------
// 256 threads, 64 nodes/block. GEMM1: th=t&15 owns hids th*8..+7, tn=t>>4 owns
// nodes tn*4..+3. x via laundered uniform vector loads, register-prefetched
// 2 chunks deep; W1 direct from L1/L2 (no staging, no barriers in GEMM1).
__global__ __launch_bounds__(256) void k_mlp(const float* __restrict__ x,
                      const float* __restrict__ W1, const float* __restrict__ b1,
                      const float* __restrict__ W2, const float* __restrict__ b2,
                      float* __restrict__ h0, int N){
  __shared__ float lds[8704];        // h1tT[128][68] = 34.8KB
  const int t    = threadIdx.x;
  const int th   = t & 15;
  const int tn   = t >> 4;
  const int lane = t & 63;
  const int wv   = __builtin_amdgcn_readfirstlane(t >> 6);   // 0..3
  const int nb   = blockIdx.x * 64;

  // laundered x row pointers: force VGPR so compiler emits vector loads
  const float* xp[4];
  #pragma unroll
  for (int j=0;j<4;++j){
    int r = nb + tn*4 + j; if (r >= N) r = N-1;
    const float* p = x + (size_t)r * F_IN;
    asm volatile("" : "+v"(p));
    xp[j] = p;
  }

  float acc[4][8];
  {
    const float4 ba = *(const float4*)(b1 + th*8);
    const float4 bb = *(const float4*)(b1 + th*8 + 4);
    #pragma unroll
    for (int j=0;j<4;++j){
      acc[j][0]=ba.x; acc[j][1]=ba.y; acc[j][2]=ba.z; acc[j][3]=ba.w;
      acc[j][4]=bb.x; acc[j][5]=bb.y; acc[j][6]=bb.z; acc[j][7]=bb.w;
    }
  }

  float4 xa[4], xb[4];
  auto loadx = [&](float4 (&buf)[4], int gk){
    const int kb = gk*4;
    #pragma unroll
    for (int j=0;j<4;++j) buf[j] = *(const float4*)(xp[j] + kb);
  };
  auto dochunk = [&](int gk, float4 (&xv)[4]){
    const float* wl = W1 + gk*512 + th*8;     // rows gk*4..+3, cols th*8..+7
    float w[4][8];
    #pragma unroll
    for (int r=0;r<4;++r){
      *(float4*)&w[r][0] = *(const float4*)(wl + r*128);
      *(float4*)&w[r][4] = *(const float4*)(wl + r*128 + 4);
    }
    float xk[4][4];
    #pragma unroll
    for (int j=0;j<4;++j){ float4 v = xv[j]; xk[j][0]=v.x; xk[j][1]=v.y; xk[j][2]=v.z; xk[j][3]=v.w; }
    #pragma unroll
    for (int r=0;r<4;++r){
      #pragma unroll
      for (int j=0;j<4;++j){
        #pragma unroll
        for (int h=0;h<8;++h)
          acc[j][h] += xk[j][r]*w[r][h];
      }
    }
  };

  loadx(xa, 0); loadx(xb, 1);
  for (int gk=0; gk<128; gk+=2){
    dochunk(gk, xa);
    { int nk = gk+2; if (nk>127) nk = 127; loadx(xa, nk); }
    dochunk(gk+1, xb);
    { int nk = gk+3; if (nk>127) nk = 127; loadx(xb, nk); }
  }

  // relu + write h1 transposed: h1tT[hid][node], pad 68 (conflict-free reads)
  #pragma unroll
  for (int h=0; h<8; ++h){
    float4 v = make_float4(fmaxf(acc[0][h],0.f), fmaxf(acc[1][h],0.f),
                           fmaxf(acc[2][h],0.f), fmaxf(acc[3][h],0.f));
    *(float4*)&lds[(th*8+h)*68 + tn*4] = v;
  }
  __syncthreads();

  // GEMM2: wave wv owns cols wv*10..+9; lane = node (all 64 lanes active).
  // h1 via conflict-free LDS b32; W2/b2 via uniform s_load (K$-resident).
  const int c0 = wv*10;
  float a2[10];
  #pragma unroll
  for (int i=0;i<10;++i) a2[i] = b2[c0+i];
  #pragma unroll 4
  for (int k=0;k<F_HID;++k){
    const float hv = lds[k*68 + lane];
    #pragma unroll
    for (int i=0;i<10;++i) a2[i] += hv * W2[k*F_OUT + c0 + i];
  }
  const int gn = nb + lane;
  if (gn < N){
    float* o = h0 + (size_t)gn*F_OUT + c0;
    #pragma unroll
    for (int i=0;i<10;++i) o[i] = fmaxf(a2[i], 0.f);
  }
}

// ---------- propagation: z' = 0.9*(A_hat z) + 0.1*h0 ----------
// 4 nodes per 256-thread block (one wave each). Rows padded to x8: no scalar
// tail. 2-deep chunk pipeline: 16 gathers in flight (counted vmcnt waits).
__global__ __launch_bounds__(256) void k_prop(const int* __restrict__ row_ptr, const int* __restrict__ csr_src,
                      const float* __restrict__ csr_norm, const float* __restrict__ dinv,
                      const float* __restrict__ zin, const float* __restrict__ h0,
                      float* __restrict__ zout, int N){
  const int wv   = __builtin_amdgcn_readfirstlane((int)(threadIdx.x >> 6));
  const int node = blockIdx.x*4 + wv;
  const int lane = threadIdx.x & 63;
  if (node >= N) return;
  if (lane >= F_OUT) return;
  const int beg = row_ptr[node];
  const int nch = (row_ptr[node+1] - beg) >> 3;   // rows are multiples of 8

  const float di = dinv[node];
  const size_t idx = (size_t)node*F_OUT + lane;
  const float zself = zin[idx];      // hoisted: in flight during loop
  const float hh    = h0[idx];

  auto loadm = [&](int (&S)[8], float (&Nm)[8], int P){
    #pragma unroll
    for (int j=0;j<8;j++){ S[j]=csr_src[P+j]; Nm[j]=csr_norm[P+j]; }
  };
  auto gath = [&](float (&Z)[8], const int (&S)[8]){
    #pragma unroll
    for (int j=0;j<8;j++){ Z[j]=zin[(size_t)S[j]*F_OUT + lane]; }
  };

  float acc = 0.f;
  if (nch > 0){
    int sA[8]; float nA[8]; float zvA[8];
    int sB[8]; float nB[8]; float zvB[8];
    loadm(sA, nA, beg); gath(zvA, sA);
    int p = beg;
    int c = 0;
    while (true){
      if (c+1 < nch){ loadm(sB, nB, p+8); gath(zvB, sB); }
      #pragma unroll
      for (int j=0;j<8;j++) acc += nA[j]*zvA[j];
      if (++c >= nch) break;
      if (c+1 < nch){ loadm(sA, nA, p+16); gath(zvA, sA); }
      #pragma unroll
      for (int j=0;j<8;j++) acc += nB[j]*zvB[j];
      if (++c >= nch) break;
      p += 16;
    }
  }

  acc += di*di*zself;
  zout[idx] = 0.9f*acc + 0.1f*hh;
}

extern "C" void kernel_launch(void* const* d_in, const int* in_sizes, int n_in,
                              void* d_out, int out_size, void* d_ws, size_t ws_size,
                              hipStream_t stream){
  const float* x  = (const float*)d_in[0];
  const int*   ei = (const int*)d_in[1];
  const float* W1 = (const float*)d_in[2];
  const float* b1 = (const float*)d_in[3];
  const float* W2 = (const float*)d_in[4];
  const float* b2 = (const float*)d_in[5];
  int N = in_sizes[0] / F_IN;
  int E = in_sizes[1] / 2;
  const int* row = ei;       // sources
  const int* col = ei + E;   // targets
  size_t EP = (size_t)E + 8*(size_t)N;   // padded-CSR capacity

  char* w = (char*)d_ws;
  auto alloc = [&](size_t bytes)->void*{ void* p = w; w += (bytes + 255) & ~255ull; return p; };
  int*   cnt      = (int*)  alloc((size_t)N*4);
  int*   cur      = (int*)  alloc((size_t)N*4);
  int*   row_ptr  = (int*)  alloc(((size_t)N+1)*4);
  float* dinv     = (float*)alloc((size_t)N*4);
  int NB = (N + SCAN_CHUNK-1)/SCAN_CHUNK;   // 196 for N=100000 (<=256)
  int*   bsum     = (int*)  alloc((size_t)NB*4);
  int*   boff     = (int*)  alloc((size_t)NB*4);
  int*   csr_src  = (int*)  alloc(EP*4);
  float* csr_norm = (float*)alloc(EP*4);
  float* h0       = (float*)alloc((size_t)N*F_OUT*4);
  float* zA       = (float*)alloc((size_t)N*F_OUT*4);
  float* zB       = (float*)alloc((size_t)N*F_OUT*4);

  (void)hipMemsetAsync(cnt, 0, (size_t)N*4, stream);
  (void)hipMemsetAsync(cur, 0, (size_t)N*4, stream);
  (void)hipMemsetAsync(csr_src, 0, EP*4, stream);    // dummy edges -> z[0]
  (void)hipMemsetAsync(csr_norm, 0, EP*4, stream);   // dummy edges weight 0

  int ge = (E + 255)/256;
  k_hist   <<<ge, 256, 0, stream>>>(col, E, cnt);
  k_dinv   <<<(N+255)/256, 256, 0, stream>>>(cnt, N, dinv);
  k_scan1  <<<NB, 256, 0, stream>>>(cnt, N, bsum);
  k_scan2  <<<1, 256, 0, stream>>>(bsum, NB, boff, row_ptr, N, E);
  k_scan3  <<<NB, 256, 0, stream>>>(cnt, N, boff, row_ptr);
  k_scatter<<<ge, 256, 0, stream>>>(row, col, E, row_ptr, cur, dinv, csr_src, csr_norm);

  k_mlp<<<(N+63)/64, 256, 0, stream>>>(x, W1, b1, W2, b2, h0, N);

  float* zi = h0; float* zo = zA;
  int gp = (N + 3)/4;
  for (int it=0; it<K_ITERS; ++it){
    float* dst = (it == K_ITERS-1) ? (float*)d_out : zo;   // final iter writes output
    k_prop<<<gp, 256, 0, stream>>>(row_ptr, csr_src, csr_norm, dinv, zi, h0, dst, N);
    float* nxt = (it==0) ? zB : zi;
    zi = zo; zo = nxt;
  }
}

// Round 4
// 2762.561 us; speedup vs baseline: 1.0526x; 1.0526x over previous
//
#include <hip/hip_runtime.h>
#include <hip/hip_bf16.h>

#define K_ITERS 20
#define F_IN 512
#define F_HID 128
#define F_OUT 40
#define NBLK 4
#define PWAVES 8192
#define MAXK 16

// Dataset is FP32 end-to-end (established round 3/6). Output buffer fp32 (16 MB).
// R10 changes:
//  - k_prop: SOURCE-BLOCKED PHASES. Sources partitioned into 4 blocks of
//    N/4 nodes (4MB of z rows = one XCD L2). CSR rebuilt with 4 per-block
//    segments per target row (padded to x4). Persistent kernel: 8192 waves,
//    all co-resident (launch_bounds(256,8)), each owning 13 nodes with
//    register accumulators, sweeping phases 0->3 in rough lockstep ->
//    gathers hit per-XCD L2 (34.5 TB/s) instead of Infinity Cache (~5 TB/s).
//    R1-R3 nulls (issue/occupancy/depth) established k_prop is BW-bound.
//  - k_mlp: reverted to R2 version (W1 LDS-dbuf; R3's unstaged variant
//    regressed 380->415).

typedef const float __attribute__((address_space(1)))* glb_fp;
typedef float __attribute__((address_space(3)))* lds_fp;

__device__ __forceinline__ int blk_of(int s, int BS){
  int b = (s >= 2*BS) ? 2 : 0;
  if (s >= (b+1)*BS) b++;
  return b;
}

// ---------- per-(target, src-block) histogram ----------
__global__ void k_hist4(const int* __restrict__ row, const int* __restrict__ col,
                        int E, int BS, int* __restrict__ cnt4){
  int e = blockIdx.x*blockDim.x + threadIdx.x;
  if (e < E) atomicAdd(&cnt4[col[e]*NBLK + blk_of(row[e], BS)], 1);
}

// ---------- dinv = rsqrt(in_deg + 1) ----------
__global__ void k_dinv4(const int* __restrict__ cnt4, int N, float* __restrict__ dinv){
  int i = blockIdx.x*blockDim.x + threadIdx.x;
  if (i < N){
    int d = cnt4[i*NBLK] + cnt4[i*NBLK+1] + cnt4[i*NBLK+2] + cnt4[i*NBLK+3];
    dinv[i] = rsqrtf((float)(d + 1));
  }
}

// ---------- scans over M=4N padded counts, chunk 2048 (256 thr x 8) ----------
__global__ void k_scan1(const int* __restrict__ cnt4, int M, int* __restrict__ bsum){
  __shared__ int sd[256];
  int base = blockIdx.x*2048 + threadIdx.x*8;
  int t = threadIdx.x;
  int s = 0;
  #pragma unroll
  for (int j=0;j<8;++j){ int i=base+j; if (i<M) s += (cnt4[i]+3)&~3; }
  sd[t] = s; __syncthreads();
  for (int off=1; off<256; off<<=1){
    int v = (t>=off)? sd[t-off] : 0;
    __syncthreads();
    sd[t] += v;
    __syncthreads();
  }
  if (t==255) bsum[blockIdx.x] = sd[255];
}
__global__ void k_scan2(const int* __restrict__ bsum, int NB, int* __restrict__ boff,
                        int* __restrict__ rp4, int M){
  __shared__ int sd[256];
  int t = threadIdx.x;
  int v = (t < NB) ? bsum[t] : 0;
  sd[t] = v; __syncthreads();
  for (int off=1; off<256; off<<=1){
    int u = (t>=off)? sd[t-off] : 0;
    __syncthreads();
    sd[t] += u;
    __syncthreads();
  }
  if (t < NB) boff[t] = sd[t] - v;
  if (t == NB-1) rp4[M] = sd[t];
}
__global__ void k_scan3(const int* __restrict__ cnt4, int M, const int* __restrict__ boff,
                        int* __restrict__ rp4){
  __shared__ int sd[256];
  int base = blockIdx.x*2048 + threadIdx.x*8;
  int t = threadIdx.x;
  int c[8]; int s = 0;
  #pragma unroll
  for (int j=0;j<8;++j){ int i=base+j; c[j] = (i<M)? ((cnt4[i]+3)&~3) : 0; s += c[j]; }
  sd[t] = s; __syncthreads();
  for (int off=1; off<256; off<<=1){
    int v = (t>=off)? sd[t-off] : 0;
    __syncthreads();
    sd[t] += v;
    __syncthreads();
  }
  int run = sd[t] - s + boff[blockIdx.x];
  #pragma unroll
  for (int j=0;j<8;++j){ int i=base+j; if (i<M) rp4[i] = run; run += c[j]; }
}

// ---------- scatter into block-segmented CSR ----------
__global__ void k_scatter4(const int* __restrict__ row, const int* __restrict__ col, int E,
                           int BS, const int* __restrict__ rp4, int* __restrict__ cur4,
                           const float* __restrict__ dinv,
                           int* __restrict__ csr_src, float* __restrict__ csr_norm){
  int e = blockIdx.x*blockDim.x + threadIdx.x;
  if (e >= E) return;
  int r = row[e], c = col[e];
  int seg = c*NBLK + blk_of(r, BS);
  int p = rp4[seg] + atomicAdd(&cur4[seg], 1);
  csr_src[p] = r;
  csr_norm[p] = dinv[r]*dinv[c];
}

// ---------- fused MLP (R2 version: W1 LDS dbuf, x via laundered vec loads) ----------
__global__ __launch_bounds__(256) void k_mlp(const float* __restrict__ x,
                      const float* __restrict__ W1, const float* __restrict__ b1,
                      const float* __restrict__ W2, const float* __restrict__ b2,
                      float* __restrict__ h0, int N){
  __shared__ float lds[8704];        // union: W1 dbuf 2x16KB | h1tT[128][68] 34.8KB
  const int t    = threadIdx.x;
  const int th   = t & 31;
  const int tn   = t >> 5;
  const int lane = t & 63;
  const int wv   = __builtin_amdgcn_readfirstlane(t >> 6);   // 0..3
  const int nb   = blockIdx.x * 64;

  const float* xp[8];
  #pragma unroll
  for (int j=0;j<8;++j){
    int r = nb + tn*8 + j; if (r >= N) r = N-1;
    const float* p = x + (size_t)r * F_IN;
    asm volatile("" : "+v"(p));
    xp[j] = p;
  }

  auto stage = [&](int kt, int b){
    const float* gs = W1 + kt*(32*128) + wv*1024 + lane*4;
    int lo = __builtin_amdgcn_readfirstlane((b*4096 + wv*1024) * 4); // bytes
    #pragma unroll
    for (int i=0;i<4;++i){
      __builtin_amdgcn_global_load_lds((glb_fp)(gs + i*256),
        (lds_fp)((char*)lds + lo + i*1024), 16, 0, 0);
    }
  };

  float acc[8][4];
  {
    float4 bb = *(const float4*)(b1 + th*4);
    #pragma unroll
    for (int j=0;j<8;++j){ acc[j][0]=bb.x; acc[j][1]=bb.y; acc[j][2]=bb.z; acc[j][3]=bb.w; }
  }

  stage(0, 0);
  __syncthreads();

  for (int kt=0; kt<16; ++kt){
    const int cur = kt & 1;
    if (kt < 15) stage(kt+1, cur^1);
    const int kbase = kt*32;
    #pragma unroll
    for (int c=0;c<8;++c){
      const int kb = kbase + c*4;
      float4 xv[8];
      #pragma unroll
      for (int j=0;j<8;++j) xv[j] = *(const float4*)(xp[j] + kb);
      const float* wl = lds + cur*4096 + c*512 + th*4;
      float4 wa = *(const float4*)(wl);
      float4 wb = *(const float4*)(wl + 128);
      float4 wc = *(const float4*)(wl + 256);
      float4 wd = *(const float4*)(wl + 384);
      #pragma unroll
      for (int j=0;j<8;++j){
        acc[j][0] += xv[j].x*wa.x; acc[j][1] += xv[j].x*wa.y; acc[j][2] += xv[j].x*wa.z; acc[j][3] += xv[j].x*wa.w;
        acc[j][0] += xv[j].y*wb.x; acc[j][1] += xv[j].y*wb.y; acc[j][2] += xv[j].y*wb.z; acc[j][3] += xv[j].y*wb.w;
        acc[j][0] += xv[j].z*wc.x; acc[j][1] += xv[j].z*wc.y; acc[j][2] += xv[j].z*wc.z; acc[j][3] += xv[j].z*wc.w;
        acc[j][0] += xv[j].w*wd.x; acc[j][1] += xv[j].w*wd.y; acc[j][2] += xv[j].w*wd.z; acc[j][3] += xv[j].w*wd.w;
      }
    }
    __syncthreads();
  }

  #pragma unroll
  for (int h=0; h<4; ++h){
    const int hid = th*4 + h;
    float4 v0 = make_float4(fmaxf(acc[0][h],0.f), fmaxf(acc[1][h],0.f),
                            fmaxf(acc[2][h],0.f), fmaxf(acc[3][h],0.f));
    float4 v1 = make_float4(fmaxf(acc[4][h],0.f), fmaxf(acc[5][h],0.f),
                            fmaxf(acc[6][h],0.f), fmaxf(acc[7][h],0.f));
    *(float4*)&lds[hid*68 + tn*8]     = v0;
    *(float4*)&lds[hid*68 + tn*8 + 4] = v1;
  }
  __syncthreads();

  const int c0 = wv*10;
  float a2[10];
  #pragma unroll
  for (int i=0;i<10;++i) a2[i] = b2[c0+i];
  #pragma unroll 4
  for (int k=0;k<F_HID;++k){
    const float hv = lds[k*68 + lane];
    #pragma unroll
    for (int i=0;i<10;++i) a2[i] += hv * W2[k*F_OUT + c0 + i];
  }
  const int gn = nb + lane;
  if (gn < N){
    float* o = h0 + (size_t)gn*F_OUT + c0;
    #pragma unroll
    for (int i=0;i<10;++i) o[i] = fmaxf(a2[i], 0.f);
  }
}

// ---------- propagation: persistent, source-blocked phases ----------
// 8192 waves co-resident; wave W owns nodes W, W+8192, ... (<=13 for N=100K),
// acc in registers. Phase p processes only edges with src in block p so all
// CUs gather from the same 4MB z window -> per-XCD L2 resident.
__global__ __launch_bounds__(256, 8) void k_prop(const int* __restrict__ rp4,
                      const int* __restrict__ csr_src, const float* __restrict__ csr_norm,
                      const float* __restrict__ dinv, const float* __restrict__ zin,
                      const float* __restrict__ h0, float* __restrict__ zout,
                      int N, int npw){
  const int wv   = __builtin_amdgcn_readfirstlane((int)(threadIdx.x >> 6));
  const int W    = blockIdx.x*4 + wv;
  const int lane = threadIdx.x & 63;
  if (lane >= F_OUT) return;

  float acc[MAXK];
  #pragma unroll
  for (int k=0;k<MAXK;++k) acc[k] = 0.f;

  for (int p=0; p<NBLK; ++p){
    #pragma unroll
    for (int k=0;k<MAXK;++k){
      const int n = W + k*PWAVES;
      if (k < npw && n < N){
        const int beg = rp4[n*NBLK + p], end = rp4[n*NBLK + p + 1];
        float a = 0.f;
        for (int q=beg; q<end; q+=4){
          int   s0=csr_src[q+0], s1=csr_src[q+1], s2=csr_src[q+2], s3=csr_src[q+3];
          float m0=csr_norm[q+0], m1=csr_norm[q+1], m2=csr_norm[q+2], m3=csr_norm[q+3];
          float z0 = zin[(size_t)s0*F_OUT + lane];
          float z1 = zin[(size_t)s1*F_OUT + lane];
          float z2 = zin[(size_t)s2*F_OUT + lane];
          float z3 = zin[(size_t)s3*F_OUT + lane];
          a += m0*z0; a += m1*z1; a += m2*z2; a += m3*z3;
        }
        acc[k] += a;
      }
    }
  }

  #pragma unroll
  for (int k=0;k<MAXK;++k){
    const int n = W + k*PWAVES;
    if (k < npw && n < N){
      const float di = dinv[n];
      const size_t idx = (size_t)n*F_OUT + lane;
      float v = acc[k] + di*di*zin[idx];
      zout[idx] = 0.9f*v + 0.1f*h0[idx];
    }
  }
}

extern "C" void kernel_launch(void* const* d_in, const int* in_sizes, int n_in,
                              void* d_out, int out_size, void* d_ws, size_t ws_size,
                              hipStream_t stream){
  const float* x  = (const float*)d_in[0];
  const int*   ei = (const int*)d_in[1];
  const float* W1 = (const float*)d_in[2];
  const float* b1 = (const float*)d_in[3];
  const float* W2 = (const float*)d_in[4];
  const float* b2 = (const float*)d_in[5];
  int N = in_sizes[0] / F_IN;
  int E = in_sizes[1] / 2;
  const int* row = ei;       // sources
  const int* col = ei + E;   // targets
  const int BS = (N + NBLK - 1)/NBLK;         // 25000 source nodes per block
  const int M  = N*NBLK;                      // segment count
  size_t EP = (size_t)E + 3ull*M;             // pad-to-4 worst case

  char* w = (char*)d_ws;
  auto alloc = [&](size_t bytes)->void*{ void* p = w; w += (bytes + 255) & ~255ull; return p; };
  int*   cnt4     = (int*)  alloc((size_t)M*4);
  int*   cur4     = (int*)  alloc((size_t)M*4);
  int*   rp4      = (int*)  alloc(((size_t)M+1)*4);
  float* dinv     = (float*)alloc((size_t)N*4);
  int NB = (M + 2047)/2048;                   // 196 for N=100000 (<=256)
  int*   bsum     = (int*)  alloc((size_t)NB*4);
  int*   boff     = (int*)  alloc((size_t)NB*4);
  int*   csr_src  = (int*)  alloc(EP*4);
  float* csr_norm = (float*)alloc(EP*4);
  float* h0       = (float*)alloc((size_t)N*F_OUT*4);
  float* zA       = (float*)alloc((size_t)N*F_OUT*4);
  float* zB       = (float*)alloc((size_t)N*F_OUT*4);

  (void)hipMemsetAsync(cnt4, 0, (size_t)M*4, stream);
  (void)hipMemsetAsync(cur4, 0, (size_t)M*4, stream);
  (void)hipMemsetAsync(csr_src, 0, EP*4, stream);    // dummy edges -> z[0] (hot line)
  (void)hipMemsetAsync(csr_norm, 0, EP*4, stream);   // dummy edges weight 0

  int ge = (E + 255)/256;
  k_hist4  <<<ge, 256, 0, stream>>>(row, col, E, BS, cnt4);
  k_dinv4  <<<(N+255)/256, 256, 0, stream>>>(cnt4, N, dinv);
  k_scan1  <<<NB, 256, 0, stream>>>(cnt4, M, bsum);
  k_scan2  <<<1, 256, 0, stream>>>(bsum, NB, boff, rp4, M);
  k_scan3  <<<NB, 256, 0, stream>>>(cnt4, M, boff, rp4);
  k_scatter4<<<ge, 256, 0, stream>>>(row, col, E, BS, rp4, cur4, dinv, csr_src, csr_norm);

  k_mlp<<<(N+63)/64, 256, 0, stream>>>(x, W1, b1, W2, b2, h0, N);

  int npw = (N + PWAVES - 1)/PWAVES;          // 13 for N=100000 (<= MAXK)
  float* zi = h0; float* zo = zA;
  for (int it=0; it<K_ITERS; ++it){
    float* dst = (it == K_ITERS-1) ? (float*)d_out : zo;   // final iter writes output
    k_prop<<<PWAVES/4, 256, 0, stream>>>(rp4, csr_src, csr_norm, dinv, zi, h0, dst, N, npw);
    float* nxt = (it==0) ? zB : zi;
    zi = zo; zo = nxt;
  }
}